// Round 9
// baseline (227.657 us; speedup 1.0000x reference)
//
#include <hip/hip_runtime.h>

#define BSZ   4
#define TSEQ  4096
#define DEMB  256
#define NTOK  (BSZ * TSEQ)   // 16384
#define HID   512
#define SPLITS 4
#define KEYS_PER_SPLIT (TSEQ / SPLITS)   // 1024
#define TK 32
#define NT (KEYS_PER_SPLIT / TK)         // 32 tiles per split
#define KIMG_STRIDE 8704    // shorts per K tile image  (17408 B = 17 x 1KB DMA)
#define VIMG_STRIDE 10240   // shorts per V^T tile image (20480 B = 20 x 1KB DMA)

using bf16x8 = __attribute__((ext_vector_type(8))) short;
using f32x16 = __attribute__((ext_vector_type(16))) float;

static __device__ __forceinline__ unsigned short f2bf(float f) {
  union { float f; unsigned u; } v; v.f = f;
  unsigned r = v.u + 0x7FFF + ((v.u >> 16) & 1);   // RNE
  return (unsigned short)(r >> 16);
}
static __device__ __forceinline__ float bf2f(unsigned short u) {
  union { unsigned u; float f; } v; v.u = ((unsigned)u) << 16;
  return v.f;
}

// async global->LDS DMA, 16 B/lane: lds dest = uniform base + lane*16
static __device__ __forceinline__ void async16(void* lds, const void* gp) {
  __builtin_amdgcn_global_load_lds(
      (const __attribute__((address_space(1))) unsigned int*)gp,
      (__attribute__((address_space(3))) unsigned int*)lds, 16, 0, 0);
}

// v_permlane32_swap_b32: a' = [a.lo32lanes, b.lo32lanes], b' = [a.hi, b.hi]
static __device__ __forceinline__ void plswap(unsigned& a, unsigned& b) {
  using uint2v = __attribute__((ext_vector_type(2))) unsigned int;
  uint2v r = __builtin_amdgcn_permlane32_swap(a, b, false, false);
  a = r[0]; b = r[1];
}

// ---------------------------------------------------------------------------
// x fp32 -> xb bf16 (RNE, bitwise-identical to the old in-qkvln conversion).
// 1024 blocks x 256 thr x 4 float4 = 16.7 MB read / 8.4 MB write, streaming.
// ---------------------------------------------------------------------------
__global__ __launch_bounds__(256) void castx_kernel(
    const float* __restrict__ x, unsigned short* __restrict__ xb)
{
  const size_t base = ((size_t)blockIdx.x * 256 + threadIdx.x) * 4;
#pragma unroll
  for (int u = 0; u < 4; ++u) {
    const size_t i = base + u;                     // float4 index
    float4 v = ((const float4*)x)[i];
    ushort4 o;
    o.x = f2bf(v.x); o.y = f2bf(v.y); o.z = f2bf(v.z); o.w = f2bf(v.w);
    ((ushort4*)xb)[i] = o;
  }
}

// ---------------------------------------------------------------------------
// Prep: y<3 -> qkv [3][K][N] fp32 -> qkvT [3][N][K] bf16 (16 tiles, x<16)
//       y=3/4 -> w1/w2 fp32 -> bf16 cast (x = 0..127)
// ---------------------------------------------------------------------------
__global__ __launch_bounds__(256) void prep_kernel(
    const float* __restrict__ qkv, const float* __restrict__ w1,
    const float* __restrict__ w2, unsigned short* __restrict__ qkvT,
    unsigned short* __restrict__ w1b, unsigned short* __restrict__ w2b)
{
  const int tid = threadIdx.x;
  if (blockIdx.y < 3) {
    if (blockIdx.x >= 16) return;
    __shared__ float Ts[64][65];
    const int z  = blockIdx.y;
    const int k0 = (blockIdx.x >> 2) * 64;
    const int j0 = (blockIdx.x & 3) * 64;
    const float* src = qkv + (size_t)z * DEMB * DEMB + (size_t)k0 * DEMB + j0;
#pragma unroll
    for (int p = 0; p < 4; ++p) {
      int idx = p * 256 + tid;
      int r = idx >> 4, g = idx & 15;
      float4 v = *(const float4*)(src + (size_t)r * DEMB + g * 4);
      Ts[r][g * 4 + 0] = v.x; Ts[r][g * 4 + 1] = v.y;
      Ts[r][g * 4 + 2] = v.z; Ts[r][g * 4 + 3] = v.w;
    }
    __syncthreads();
    unsigned short* dst = qkvT + (size_t)z * DEMB * DEMB + (size_t)j0 * DEMB + k0;
#pragma unroll
    for (int p = 0; p < 4; ++p) {
      int idx = p * 256 + tid;
      int r = idx >> 4, g = idx & 15;
      ushort4 o;
      o.x = f2bf(Ts[g * 4 + 0][r]); o.y = f2bf(Ts[g * 4 + 1][r]);
      o.z = f2bf(Ts[g * 4 + 2][r]); o.w = f2bf(Ts[g * 4 + 3][r]);
      *(ushort4*)(dst + (size_t)r * DEMB + g * 4) = o;
    }
  } else {
    const float* s = (blockIdx.y == 3) ? w1 : w2;
    unsigned short* d = (blockIdx.y == 3) ? w1b : w2b;
    const int i = blockIdx.x * 256 + tid;
    float4 v = ((const float4*)s)[i];
    ushort4 o;
    o.x = f2bf(v.x); o.y = f2bf(v.y); o.z = f2bf(v.z); o.w = f2bf(v.w);
    ((ushort4*)d)[i] = o;
  }
}

// ---------------------------------------------------------------------------
// Fused QKV projection + LN(Q/K) + V-transpose.
// 512 thr (8 waves), 256-token x 256-col tile, grid (NTOK/256, 3) = 192 blocks
// (all co-resident). A-operand now pre-cast bf16 (xb): staging is 4x bf16x8
// loads + 4x ds_write_b128 per k-tile, no in-loop f2bf (was 8x float4 + 32
// f2bf + 8x ds_write_b64 -- the conversion VALU serialized against MFMA).
// z=0: Q -> LN -> Qbn linear. z=1: K -> LN -> Kimg tiles. z=2: V -> LDS-
// transpose -> Vimg tiles. LN in-register (xor-shuffle stats over lm).
// ---------------------------------------------------------------------------
__global__ __launch_bounds__(512, 1) void qkvln_kernel(
    const unsigned short* __restrict__ xb, const unsigned short* __restrict__ qkvT,
    const float* __restrict__ lnqw, const float* __restrict__ lnqb,
    const float* __restrict__ lnkw, const float* __restrict__ lnkb,
    unsigned short* __restrict__ Qbn, unsigned short* __restrict__ Kimg,
    unsigned short* __restrict__ Vimg)
{
  __shared__ __align__(16) unsigned short sh[36864];  // As 256x72 | Bs 256x72
  unsigned short* As = sh;
  unsigned short* Bs = sh + 256 * 72;

  const int tid = threadIdx.x;
  const int w   = tid >> 6;      // 0..7, rows w*32..+31
  const int l   = tid & 63;
  const int lm  = l & 31;
  const int lh  = l >> 5;
  const int z   = blockIdx.y;
  const int m0  = blockIdx.x * 256;
  const int bb  = m0 >> 12;      // batch (256 | 4096)

  const unsigned short* Bt = qkvT + (size_t)z * DEMB * DEMB;

  f32x16 o[8];
#pragma unroll
  for (int t = 0; t < 8; ++t)
#pragma unroll
    for (int r = 0; r < 16; ++r) o[t][r] = 0.f;

  bf16x8 arb[4], brb[4];

  // preload k0 = 0  (c = tid + 512i: row = c>>3 in [0,256), col = (c&7)*8)
#pragma unroll
  for (int i = 0; i < 4; ++i) {
    const int c = tid + 512 * i;
    arb[i] = *(const bf16x8*)(xb + (size_t)(m0 + (c >> 3)) * DEMB + (c & 7) * 8);
    brb[i] = *(const bf16x8*)(Bt + (size_t)(c >> 3) * DEMB + (c & 7) * 8);
  }

  for (int k0 = 0; k0 < DEMB; k0 += 64) {
    __syncthreads();
#pragma unroll
    for (int i = 0; i < 4; ++i) {
      const int c = tid + 512 * i;
      *(bf16x8*)&As[(c >> 3) * 72 + (c & 7) * 8] = arb[i];
      *(bf16x8*)&Bs[(c >> 3) * 72 + (c & 7) * 8] = brb[i];
    }
    __syncthreads();

    if (k0 + 64 < DEMB) {
      const int kn = k0 + 64;
#pragma unroll
      for (int i = 0; i < 4; ++i) {
        const int c = tid + 512 * i;
        arb[i] = *(const bf16x8*)(xb + (size_t)(m0 + (c >> 3)) * DEMB + kn + (c & 7) * 8);
        brb[i] = *(const bf16x8*)(Bt + (size_t)(c >> 3) * DEMB + kn + (c & 7) * 8);
      }
    }

#pragma unroll
    for (int ks = 0; ks < 4; ++ks) {
      bf16x8 a = *(const bf16x8*)&As[(w * 32 + lm) * 72 + ks * 16 + lh * 8];
#pragma unroll
      for (int t = 0; t < 8; ++t) {
        bf16x8 b = *(const bf16x8*)&Bs[(t * 32 + lm) * 72 + ks * 16 + lh * 8];
        o[t] = __builtin_amdgcn_mfma_f32_32x32x16_bf16(a, b, o[t], 0, 0, 0);
      }
    }
  }

  __syncthreads();   // all LDS frag reads done before epilogue reuse

  if (z < 2) {
    // ---- LayerNorm in-register, write Qbn (linear) or Kimg (tile image) ----
    const float* wp = z ? lnkw : lnqw;
    const float* bp = z ? lnkb : lnqb;
    float wc[8], bc[8];
#pragma unroll
    for (int t = 0; t < 8; ++t) { wc[t] = wp[t * 32 + lm]; bc[t] = bp[t * 32 + lm]; }
#pragma unroll
    for (int r = 0; r < 16; ++r) {
      float sv = 0.f, sq = 0.f;
#pragma unroll
      for (int t = 0; t < 8; ++t) { const float v = o[t][r]; sv += v; sq += v * v; }
#pragma unroll
      for (int d = 1; d < 32; d <<= 1) { sv += __shfl_xor(sv, d, 64); sq += __shfl_xor(sq, d, 64); }
      const float mean = sv * (1.f / DEMB);
      const float rs = rsqrtf(sq * (1.f / DEMB) - mean * mean + 1e-5f);
      const int token = m0 + w * 32 + (r & 3) + 8 * (r >> 2) + 4 * lh;
      if (z == 0) {
        unsigned short* dst = Qbn + (size_t)token * DEMB;
#pragma unroll
        for (int t = 0; t < 8; ++t)
          dst[t * 32 + lm] = f2bf((o[t][r] - mean) * rs * wc[t] + bc[t]);
      } else {
        const int t5 = token & 4095;
        unsigned short* dst =
            Kimg + (size_t)(bb * 128 + (t5 >> 5)) * KIMG_STRIDE + (t5 & 31) * 264;
#pragma unroll
        for (int t = 0; t < 8; ++t)
          dst[t * 32 + lm] = f2bf((o[t][r] - mean) * rs * wc[t] + bc[t]);
      }
    }
  } else {
    // ---- V: transpose via LDS (pitch 130 shorts = 65 dw, conflict-free) ----
#pragma unroll
    for (int h = 0; h < 2; ++h) {
      if (h) __syncthreads();
#pragma unroll
      for (int t2 = 0; t2 < 4; ++t2) {
        const int t = h * 4 + t2;
#pragma unroll
        for (int r = 0; r < 16; ++r) {
          const int row = w * 32 + (r & 3) + 8 * (r >> 2) + 4 * lh;
          sh[row * 130 + t2 * 32 + lm] = f2bf(o[t][r]);
        }
      }
      __syncthreads();
      const int d2 = tid & 127;          // local d within half
      const int tq = tid >> 7;           // 0..3, tokens tq*64..+63
      const int d  = h * 128 + d2;
#pragma unroll
      for (int j = 0; j < 16; ++j) {
        const int tok0 = tq * 64 + j * 4;
        ushort4 v;
        v.x = sh[(tok0 + 0) * 130 + d2];
        v.y = sh[(tok0 + 1) * 130 + d2];
        v.z = sh[(tok0 + 2) * 130 + d2];
        v.w = sh[(tok0 + 3) * 130 + d2];
        const int gtok = m0 + tok0;
        const int kt = (gtok & 4095) >> 5;
        *(ushort4*)(Vimg + (size_t)(bb * 128 + kt) * VIMG_STRIDE + d * 40 + (tok0 & 31)) = v;
      }
    }
  }
}

// ---------------------------------------------------------------------------
// bf16 MFMA GEMM, bf16 in / bf16 out, leaky-relu. C = act(A @ Bt^T).
// 128x128 tile, 4 waves, 2x2 MFMA subtiles/wave, pipelined K-loop.
// ---------------------------------------------------------------------------
__global__ __launch_bounds__(256, 3) void gemm_ffn_kernel(
    const unsigned short* __restrict__ A, const unsigned short* __restrict__ Bt,
    unsigned short* __restrict__ C, int M, int N, int K)
{
  __shared__ __align__(16) unsigned short As[128 * 72];
  __shared__ __align__(16) unsigned short Bs[128 * 72];

  const int tid = threadIdx.x;
  const int w   = tid >> 6;
  const int wm  = w >> 1, wn = w & 1;
  const int l   = tid & 63;
  const int lm  = l & 31;
  const int lh  = l >> 5;

  const int m0    = blockIdx.x * 128;
  const int nbase = blockIdx.y * 128;

  f32x16 acc00, acc01, acc10, acc11;
#pragma unroll
  for (int r = 0; r < 16; ++r) { acc00[r] = 0.f; acc01[r] = 0.f; acc10[r] = 0.f; acc11[r] = 0.f; }

  const int lr = tid >> 3;
  const int lc = (tid & 7) * 8;

  bf16x8 arb[4], brb[4];

#pragma unroll
  for (int i = 0; i < 4; ++i) {
    arb[i] = *(const bf16x8*)(A  + (size_t)(m0 + i * 32 + lr) * K + lc);
    brb[i] = *(const bf16x8*)(Bt + (size_t)(nbase + i * 32 + lr) * K + lc);
  }

  for (int k0 = 0; k0 < K; k0 += 64) {
    __syncthreads();
#pragma unroll
    for (int i = 0; i < 4; ++i) {
      *(bf16x8*)&As[(i * 32 + lr) * 72 + lc] = arb[i];
      *(bf16x8*)&Bs[(i * 32 + lr) * 72 + lc] = brb[i];
    }
    __syncthreads();

    if (k0 + 64 < K) {
      const int kn = k0 + 64;
#pragma unroll
      for (int i = 0; i < 4; ++i) {
        arb[i] = *(const bf16x8*)(A  + (size_t)(m0 + i * 32 + lr) * K + kn + lc);
        brb[i] = *(const bf16x8*)(Bt + (size_t)(nbase + i * 32 + lr) * K + kn + lc);
      }
    }

#pragma unroll
    for (int ks = 0; ks < 4; ++ks) {
      bf16x8 a0 = *(const bf16x8*)&As[(wm * 64 + lm)      * 72 + ks * 16 + lh * 8];
      bf16x8 a1 = *(const bf16x8*)&As[(wm * 64 + 32 + lm) * 72 + ks * 16 + lh * 8];
      bf16x8 b0 = *(const bf16x8*)&Bs[(wn * 64 + lm)      * 72 + ks * 16 + lh * 8];
      bf16x8 b1 = *(const bf16x8*)&Bs[(wn * 64 + 32 + lm) * 72 + ks * 16 + lh * 8];
      acc00 = __builtin_amdgcn_mfma_f32_32x32x16_bf16(a0, b0, acc00, 0, 0, 0);
      acc01 = __builtin_amdgcn_mfma_f32_32x32x16_bf16(a0, b1, acc01, 0, 0, 0);
      acc10 = __builtin_amdgcn_mfma_f32_32x32x16_bf16(a1, b0, acc10, 0, 0, 0);
      acc11 = __builtin_amdgcn_mfma_f32_32x32x16_bf16(a1, b1, acc11, 0, 0, 0);
    }
  }

  const f32x16* accs[4] = { &acc00, &acc01, &acc10, &acc11 };
#pragma unroll
  for (int am = 0; am < 2; ++am)
#pragma unroll
    for (int bn = 0; bn < 2; ++bn) {
      const f32x16& a = *accs[am * 2 + bn];
#pragma unroll
      for (int r = 0; r < 16; ++r) {
        const int m = m0 + wm * 64 + am * 32 + (r & 3) + 8 * (r >> 2) + 4 * lh;
        const int n = nbase + wn * 64 + bn * 32 + lm;
        float v = a[r];
        v = v > 0.f ? v : 0.2f * v;
        C[(size_t)m * N + n] = f2bf(v);
      }
    }
}

// Out = 0.7f * (Xin + LN(Y)), Y bf16; aliasing Out==Xin safe.
__global__ __launch_bounds__(256) void ln_res_bf16_kernel(
    const unsigned short* __restrict__ Y, const float* __restrict__ Xin,
    const float* __restrict__ w, const float* __restrict__ b,
    float* __restrict__ Out)
{
  const int lane = threadIdx.x & 63;
  const size_t row = (size_t)blockIdx.x * 4 + (threadIdx.x >> 6);
  ushort4 u = *(const ushort4*)&Y[row * DEMB + lane * 4];
  float y0 = bf2f(u.x), y1 = bf2f(u.y), y2 = bf2f(u.z), y3 = bf2f(u.w);
  float s  = y0 + y1 + y2 + y3;
  float sq = y0 * y0 + y1 * y1 + y2 * y2 + y3 * y3;
#pragma unroll
  for (int o = 32; o > 0; o >>= 1) { s += __shfl_down(s, o); sq += __shfl_down(sq, o); }
  s = __shfl(s, 0); sq = __shfl(sq, 0);
  const float m  = s * (1.f / DEMB);
  const float rs = rsqrtf(sq * (1.f / DEMB) - m * m + 1e-5f);
  const float4 wv = *(const float4*)&w[lane * 4];
  const float4 bv = *(const float4*)&b[lane * 4];
  const float4 xi = *(const float4*)&Xin[row * DEMB + lane * 4];
  float4 o;
  o.x = 0.7f * (xi.x + (y0 - m) * rs * wv.x + bv.x);
  o.y = 0.7f * (xi.y + (y1 - m) * rs * wv.y + bv.y);
  o.z = 0.7f * (xi.z + (y2 - m) * rs * wv.z + bv.z);
  o.w = 0.7f * (xi.w + (y3 - m) * rs * wv.w + bv.w);
  *(float4*)&Out[row * DEMB + lane * 4] = o;
}

// ---------------------------------------------------------------------------
// Split-K MFMA flash attention (v4, best measured): QK(j) 1:1-interleaved
// with PV(j-1) so the 16-deep QK dep chain is spaced by independent PV MFMAs.
// SM(j) post-barrier, overlapping the other resident block's MFMA window.
// One barrier/tile; K dbuf + V dbuf; LDS 75776 B -> 2 blocks/CU (the two
// decorrelated barrier groups per CU are the key: one block's SM/barrier
// bubble is filled by the other's MFMA window).
// ---------------------------------------------------------------------------
__global__ __launch_bounds__(256, 2) void attn_split_kernel(
    const unsigned short* __restrict__ Qb, const unsigned short* __restrict__ Kimg,
    const unsigned short* __restrict__ Vimg, unsigned short* __restrict__ Opart,
    float* __restrict__ lpart)
{
  __shared__ __align__(16) unsigned short Ks[2][KIMG_STRIDE];   // 34816 B
  __shared__ __align__(16) unsigned short Vs[2][VIMG_STRIDE];   // 40960 B

  const int tid = threadIdx.x;
  const int w   = tid >> 6;          // 0..3
  const int l   = tid & 63;
  const int lm  = l & 31;
  const int lh  = l >> 5;

  const int lin = blockIdx.x;        // 0..511
  const int xcd = lin & 7;
  const int idx = lin >> 3;          // 0..63
  const int b     = xcd >> 1;
  const int split = (xcd & 1) * 2 + (idx & 1);
  const int q0    = (idx >> 1) * 128;

  const unsigned short* Qbase  = Qb + (size_t)b * TSEQ * DEMB;
  const unsigned short* Ktiles = Kimg + (size_t)(b * 128 + split * 32) * KIMG_STRIDE;
  const unsigned short* Vtiles = Vimg + (size_t)(b * 128 + split * 32) * VIMG_STRIDE;

  // Q fragments (B-operand of swapped QK): lane holds q-row lm of this wave
  bf16x8 qf[16];
  {
    const unsigned short* qrow = Qbase + (size_t)(q0 + w * 32 + lm) * DEMB + lh * 8;
#pragma unroll
    for (int ks = 0; ks < 16; ++ks) qf[ks] = *(const bf16x8*)(qrow + ks * 16);
  }

  f32x16 o[8];
#pragma unroll
  for (int t = 0; t < 8; ++t)
#pragma unroll
    for (int r = 0; r < 16; ++r) o[t][r] = 0.f;
  float psum = 0.f;

  bf16x8 pva, pvb;   // P(j) fragments, produced by SM(j), consumed by PV(j)

  auto DMAK = [&](int t, int buf) {
    const unsigned short* kp = Ktiles + (size_t)t * KIMG_STRIDE;
#pragma unroll
    for (int i = 0; i < 5; ++i) {
      const int c = w + 4 * i;
      if (c < 17) async16(&Ks[buf][c * 512], kp + c * 512 + l * 8);
    }
  };
  auto DMAV = [&](int t, int buf) {
    const unsigned short* vp = Vtiles + (size_t)t * VIMG_STRIDE;
#pragma unroll
    for (int i = 0; i < 5; ++i) {
      const int c = w + 4 * i;                 // 0..19, all used
      async16(&Vs[buf][c * 512], vp + c * 512 + l * 8);
    }
  };
  auto QK = [&](int buf) {
    f32x16 s;
#pragma unroll
    for (int r = 0; r < 16; ++r) s[r] = 0.f;
    const unsigned short* Kp = &Ks[buf][0];
#pragma unroll
    for (int ks = 0; ks < 16; ++ks) {
      bf16x8 kf = *(const bf16x8*)&Kp[lm * 264 + ks * 16 + lh * 8];
      s = __builtin_amdgcn_mfma_f32_32x32x16_bf16(kf, qf[ks], s, 0, 0, 0);
    }
    return s;
  };
  auto PV = [&](int buf) {
    const unsigned short* Vp = &Vs[buf][0];
#pragma unroll
    for (int t = 0; t < 8; ++t) {
      bf16x8 vf0 = *(const bf16x8*)&Vp[(t * 32 + lm) * 40 + lh * 8];
      o[t] = __builtin_amdgcn_mfma_f32_32x32x16_bf16(pva, vf0, o[t], 0, 0, 0);
      bf16x8 vf1 = *(const bf16x8*)&Vp[(t * 32 + lm) * 40 + 16 + lh * 8];
      o[t] = __builtin_amdgcn_mfma_f32_32x32x16_bf16(pvb, vf1, o[t], 0, 0, 0);
    }
  };
  auto SM = [&](const f32x16& s) {
    // s[r] = score(q=lm, tok=(r&3)+8*(r>>2)+4*lh); fixed-offset softmax.
    float e[16];
#pragma unroll
    for (int i = 0; i < 16; ++i)
      e[i] = exp2f(s[i] * 0.09016844335f - 11.541560327f);
    const float t0 = (e[0] + e[1]) + (e[2] + e[3]);
    const float t1 = (e[4] + e[5]) + (e[6] + e[7]);
    const float t2 = (e[8] + e[9]) + (e[10] + e[11]);
    const float t3 = (e[12] + e[13]) + (e[14] + e[15]);
    psum += (t0 + t1) + (t2 + t3);
    unsigned pk[8];
#pragma unroll
    for (int i = 0; i < 8; ++i)
      asm("v_cvt_pk_bf16_f32 %0, %1, %2" : "=v"(pk[i]) : "v"(e[2 * i]), "v"(e[2 * i + 1]));
    plswap(pk[0], pk[2]);   // -> dwords 0,2 of pva (tokens 0..15)
    plswap(pk[1], pk[3]);   // -> dwords 1,3 of pva
    plswap(pk[4], pk[6]);   // -> dwords 0,2 of pvb (tokens 16..31)
    plswap(pk[5], pk[7]);   // -> dwords 1,3 of pvb
    union U8 { unsigned u[4]; bf16x8 v; } A, B;
    A.u[0] = pk[0]; A.u[1] = pk[1]; A.u[2] = pk[2]; A.u[3] = pk[3];
    B.u[0] = pk[4]; B.u[1] = pk[5]; B.u[2] = pk[6]; B.u[3] = pk[7];
    pva = A.v; pvb = B.v;
  };

  // ---- prologue ----
  DMAK(0, 0); DMAV(0, 0);
  __syncthreads();                    // K0,V0 landed (vmcnt0 drain)
  DMAK(1, 1);
  f32x16 s = QK(0);
  __syncthreads();                    // all waves done reading Ks[0]; K1 landed
  DMAV(1, 1);
  SM(s);                              // -> pva/pvb = P(0)

  // ---- steady state: seg j = QK(j) 1:1-interleaved with PV(j-1), then
  //      sync, DMA-V(j+1), SM(j). Alternation keeps the s-chain's dependent
  //      MFMAs 2 issue-slots apart (o[t] chains fill the latency). ----
  for (int j = 1; j < NT; ++j) {
    const int kc = j & 1, kn = kc ^ 1;
    if (j + 1 < NT) DMAK(j + 1, kn);  // WAR ok: QK(j-1) read Ks[kn] pre-sync(j-1)
    const unsigned short* Kp = &Ks[kc][0];
    const unsigned short* Vp = &Vs[kn][0];
    f32x16 sn;
#pragma unroll
    for (int r = 0; r < 16; ++r) sn[r] = 0.f;
    __builtin_amdgcn_s_setprio(1);
#pragma unroll
    for (int i = 0; i < 16; ++i) {
      bf16x8 kf = *(const bf16x8*)&Kp[lm * 264 + i * 16 + lh * 8];
      sn = __builtin_amdgcn_mfma_f32_32x32x16_bf16(kf, qf[i], sn, 0, 0, 0);
      if (i < 8) {
        bf16x8 vf = *(const bf16x8*)&Vp[(i * 32 + lm) * 40 + lh * 8];
        o[i] = __builtin_amdgcn_mfma_f32_32x32x16_bf16(pva, vf, o[i], 0, 0, 0);
      } else {
        bf16x8 vf = *(const bf16x8*)&Vp[((i - 8) * 32 + lm) * 40 + 16 + lh * 8];
        o[i - 8] = __builtin_amdgcn_mfma_f32_32x32x16_bf16(pvb, vf, o[i - 8], 0, 0, 0);
      }
    }
    __builtin_amdgcn_s_setprio(0);
    s = sn;
    __syncthreads();                  // cross-wave fence + vmcnt0 (drains K(j+1), V(j))
    if (j + 1 < NT) DMAV(j + 1, kn);  // buffer just released by PV(j-1)
    SM(s);                            // -> P(j); overlaps other block's MFMA window
  }

  // ---- epilogue: last PV ----
  PV((NT - 1) & 1);

  // denominator for q-row lm: this lane's tokens + partner half (lh^1)
  const float tot = psum + __shfl_xor(psum, 32, 64);

  unsigned short* Ob =
      Opart + ((size_t)split * NTOK + (size_t)b * TSEQ + q0 + w * 32) * DEMB;
  float* lb = lpart + (size_t)split * NTOK + (size_t)b * TSEQ + q0 + w * 32;
#pragma unroll
  for (int r = 0; r < 16; ++r) {
    const int row = (r & 3) + ((r >> 2) << 3) + (lh << 2);
#pragma unroll
    for (int t = 0; t < 8; ++t)
      Ob[(size_t)row * DEMB + t * 32 + lm] = f2bf(o[t][r]);
  }
  if (lh == 0) lb[lm] = tot;
}

// ---------------------------------------------------------------------------
// Combine partials + attn LayerNorm + residual; emits fp32 x1 and bf16 copy.
// ---------------------------------------------------------------------------
__global__ __launch_bounds__(256) void combine_lnres_kernel(
    const unsigned short* __restrict__ Opart, const float* __restrict__ lpart,
    const float* __restrict__ Xin, const float* __restrict__ w,
    const float* __restrict__ b, float* __restrict__ Out,
    unsigned short* __restrict__ Outb)
{
  const int lane = threadIdx.x & 63;
  const size_t row = (size_t)blockIdx.x * 4 + (threadIdx.x >> 6);
  float4 acc = make_float4(0.f, 0.f, 0.f, 0.f);
  float lt = 0.f;
#pragma unroll
  for (int p = 0; p < SPLITS; ++p) {
    const ushort4 u = *(const ushort4*)&Opart[((size_t)p * NTOK + row) * DEMB + lane * 4];
    acc.x += bf2f(u.x); acc.y += bf2f(u.y);
    acc.z += bf2f(u.z); acc.w += bf2f(u.w);
    lt += lpart[(size_t)p * NTOK + row];
  }
  const float inv = 1.f / lt;
  const float y0 = acc.x * inv, y1 = acc.y * inv, y2 = acc.z * inv, y3 = acc.w * inv;
  float s  = y0 + y1 + y2 + y3;
  float sq = y0 * y0 + y1 * y1 + y2 * y2 + y3 * y3;
#pragma unroll
  for (int o = 32; o > 0; o >>= 1) { s += __shfl_down(s, o); sq += __shfl_down(sq, o); }
  s = __shfl(s, 0); sq = __shfl(sq, 0);
  const float m  = s * (1.f / DEMB);
  const float rs = rsqrtf(sq * (1.f / DEMB) - m * m + 1e-5f);
  const float4 wv = *(const float4*)&w[lane * 4];
  const float4 bv = *(const float4*)&b[lane * 4];
  const float4 xi = *(const float4*)&Xin[row * DEMB + lane * 4];
  float4 o;
  o.x = 0.7f * (xi.x + (y0 - m) * rs * wv.x + bv.x);
  o.y = 0.7f * (xi.y + (y1 - m) * rs * wv.y + bv.y);
  o.z = 0.7f * (xi.z + (y2 - m) * rs * wv.z + bv.z);
  o.w = 0.7f * (xi.w + (y3 - m) * rs * wv.w + bv.w);
  *(float4*)&Out[row * DEMB + lane * 4] = o;
  ushort4 ob;
  ob.x = f2bf(o.x); ob.y = f2bf(o.y); ob.z = f2bf(o.z); ob.w = f2bf(o.w);
  *(ushort4*)&Outb[row * DEMB + lane * 4] = ob;
}

// ---------------------------------------------------------------------------
extern "C" void kernel_launch(void* const* d_in, const int* in_sizes, int n_in,
                              void* d_out, int out_size, void* d_ws, size_t ws_size,
                              hipStream_t stream)
{
  (void)in_sizes; (void)n_in; (void)out_size; (void)ws_size;
  const float* x    = (const float*)d_in[0];
  const float* qkv  = (const float*)d_in[1];
  const float* lnqw = (const float*)d_in[2];
  const float* lnqb = (const float*)d_in[3];
  const float* lnkw = (const float*)d_in[4];
  const float* lnkb = (const float*)d_in[5];
  const float* lnaw = (const float*)d_in[6];
  const float* lnab = (const float*)d_in[7];
  const float* w1   = (const float*)d_in[8];
  const float* w2   = (const float*)d_in[9];
  const float* lnfw = (const float*)d_in[10];
  const float* lnfb = (const float*)d_in[11];
  float* out = (float*)d_out;

  // byte-offset workspace (lifetimes disjoint):
  //   Qbn[0,8) Kimg[8,17) Vimg[17,28) Opart[28,60) lpart@60
  //   xb[28,36.4) (dead before attn writes Opart)
  //   x1b[0,8) (Qbn dead after attn)  H[8,24) (Kimg/Vimg dead)
  //   Y2b[28,36) (Opart dead after combine)  qkvT@60.5 w1b@61 w2b@61.25
  char* W = (char*)d_ws;
  const size_t MB = 1 << 20;
  unsigned short* Qbn   = (unsigned short*)(W + 0);
  unsigned short* Kimg  = (unsigned short*)(W + 8 * MB);    // 8.9 MB
  unsigned short* Vimg  = (unsigned short*)(W + 17 * MB);   // 10.5 MB
  unsigned short* Opart = (unsigned short*)(W + 28 * MB);   // 32 MB
  float*          lpart = (float*)(W + 60 * MB);            // 256 KB
  unsigned short* xb    = (unsigned short*)(W + 28 * MB);   // 8.4 MB (pre-attn)
  unsigned short* x1b   = (unsigned short*)(W + 0);
  unsigned short* H     = (unsigned short*)(W + 8 * MB);
  unsigned short* Y2b   = (unsigned short*)(W + 28 * MB);
  unsigned short* qkvT  = (unsigned short*)(W + 60 * MB + 512 * 1024);  // 384 KB
  unsigned short* w1b   = (unsigned short*)(W + 61 * MB);               // 256 KB
  unsigned short* w2b   = (unsigned short*)(W + 61 * MB + 256 * 1024);  // 256 KB

  const dim3 blk(256);

  // x fp32 -> bf16 (once), weight prep: qkv transpose+cast + w1/w2 cast
  castx_kernel<<<dim3(1024), blk, 0, stream>>>(x, xb);
  prep_kernel<<<dim3(128, 5), blk, 0, stream>>>(qkv, w1, w2, qkvT, w1b, w2b);

  // fused QKV projection + LN(Q/K) + V-transpose (192 blocks, all resident)
  qkvln_kernel<<<dim3(NTOK / 256, 3), dim3(512), 0, stream>>>(
      xb, qkvT, lnqw, lnqb, lnkw, lnkb, Qbn, Kimg, Vimg);

  // attention (split-K, interleaved QK/PV pipeline) + combine/LN/residual
  attn_split_kernel<<<dim3(512), dim3(256), 0, stream>>>(Qbn, Kimg, Vimg, Opart, lpart);
  combine_lnres_kernel<<<NTOK / 4, blk, 0, stream>>>(Opart, lpart, x, lnaw, lnab, out, x1b);

  // FFN (bf16 weights, bf16 out)
  gemm_ffn_kernel<<<dim3(NTOK / 128, HID / 128), blk, 0, stream>>>(
      x1b, w1b, H, NTOK, HID, DEMB);
  gemm_ffn_kernel<<<dim3(NTOK / 128, DEMB / 128), blk, 0, stream>>>(
      H, w2b, Y2b, NTOK, DEMB, HID);

  // out = 0.7*(x1 + LN(y2))
  ln_res_bf16_kernel<<<NTOK / 4, blk, 0, stream>>>(Y2b, out, lnfw, lnfb, out);
}

// Round 10
// 216.049 us; speedup vs baseline: 1.0537x; 1.0537x over previous
//
#include <hip/hip_runtime.h>

#define BSZ   4
#define TSEQ  4096
#define DEMB  256
#define NTOK  (BSZ * TSEQ)   // 16384
#define HID   512
#define SPLITS 4
#define KEYS_PER_SPLIT (TSEQ / SPLITS)   // 1024
#define TK 32
#define NT (KEYS_PER_SPLIT / TK)         // 32 tiles per split
#define KIMG_STRIDE 8704    // shorts per K tile image  (17408 B = 17 x 1KB DMA)
#define VIMG_STRIDE 10240   // shorts per V^T tile image (20480 B = 20 x 1KB DMA)

using bf16x8 = __attribute__((ext_vector_type(8))) short;
using f32x16 = __attribute__((ext_vector_type(16))) float;

static __device__ __forceinline__ unsigned short f2bf(float f) {
  union { float f; unsigned u; } v; v.f = f;
  unsigned r = v.u + 0x7FFF + ((v.u >> 16) & 1);   // RNE
  return (unsigned short)(r >> 16);
}
static __device__ __forceinline__ float bf2f(unsigned short u) {
  union { unsigned u; float f; } v; v.u = ((unsigned)u) << 16;
  return v.f;
}

// async global->LDS DMA, 16 B/lane: lds dest = uniform base + lane*16
static __device__ __forceinline__ void async16(void* lds, const void* gp) {
  __builtin_amdgcn_global_load_lds(
      (const __attribute__((address_space(1))) unsigned int*)gp,
      (__attribute__((address_space(3))) unsigned int*)lds, 16, 0, 0);
}

// v_permlane32_swap_b32: a' = [a.lo32lanes, b.lo32lanes], b' = [a.hi, b.hi]
static __device__ __forceinline__ void plswap(unsigned& a, unsigned& b) {
  using uint2v = __attribute__((ext_vector_type(2))) unsigned int;
  uint2v r = __builtin_amdgcn_permlane32_swap(a, b, false, false);
  a = r[0]; b = r[1];
}

// ---------------------------------------------------------------------------
// Prep: y<3 -> qkv [3][K][N] fp32 -> qkvT [3][N][K] bf16 (16 tiles, x<16)
//       y=3/4 -> w1/w2 fp32 -> bf16 cast (x = 0..127)
// ---------------------------------------------------------------------------
__global__ __launch_bounds__(256) void prep_kernel(
    const float* __restrict__ qkv, const float* __restrict__ w1,
    const float* __restrict__ w2, unsigned short* __restrict__ qkvT,
    unsigned short* __restrict__ w1b, unsigned short* __restrict__ w2b)
{
  const int tid = threadIdx.x;
  if (blockIdx.y < 3) {
    if (blockIdx.x >= 16) return;
    __shared__ float Ts[64][65];
    const int z  = blockIdx.y;
    const int k0 = (blockIdx.x >> 2) * 64;
    const int j0 = (blockIdx.x & 3) * 64;
    const float* src = qkv + (size_t)z * DEMB * DEMB + (size_t)k0 * DEMB + j0;
#pragma unroll
    for (int p = 0; p < 4; ++p) {
      int idx = p * 256 + tid;
      int r = idx >> 4, g = idx & 15;
      float4 v = *(const float4*)(src + (size_t)r * DEMB + g * 4);
      Ts[r][g * 4 + 0] = v.x; Ts[r][g * 4 + 1] = v.y;
      Ts[r][g * 4 + 2] = v.z; Ts[r][g * 4 + 3] = v.w;
    }
    __syncthreads();
    unsigned short* dst = qkvT + (size_t)z * DEMB * DEMB + (size_t)j0 * DEMB + k0;
#pragma unroll
    for (int p = 0; p < 4; ++p) {
      int idx = p * 256 + tid;
      int r = idx >> 4, g = idx & 15;
      ushort4 o;
      o.x = f2bf(Ts[g * 4 + 0][r]); o.y = f2bf(Ts[g * 4 + 1][r]);
      o.z = f2bf(Ts[g * 4 + 2][r]); o.w = f2bf(Ts[g * 4 + 3][r]);
      *(ushort4*)(dst + (size_t)r * DEMB + g * 4) = o;
    }
  } else {
    const float* s = (blockIdx.y == 3) ? w1 : w2;
    unsigned short* d = (blockIdx.y == 3) ? w1b : w2b;
    const int i = blockIdx.x * 256 + tid;
    float4 v = ((const float4*)s)[i];
    ushort4 o;
    o.x = f2bf(v.x); o.y = f2bf(v.y); o.z = f2bf(v.z); o.w = f2bf(v.w);
    ((ushort4*)d)[i] = o;
  }
}

// ---------------------------------------------------------------------------
// Fused QKV projection + LN(Q/K) + V-transpose.
// 512 thr (8 waves), 256-token x 256-col tile, grid (NTOK/256, 3) = 192 blocks
// (all co-resident). z=0: Q -> LN -> Qbn linear. z=1: K -> LN -> Kimg tiles.
// z=2: V -> LDS-transpose -> Vimg tiles. LN is in-register: C-layout rows are
// lane-private per reg; stats = 8 adds + 5 xor-shuffles over lm.
// ---------------------------------------------------------------------------
__global__ __launch_bounds__(512, 1) void qkvln_kernel(
    const float* __restrict__ x, const unsigned short* __restrict__ qkvT,
    const float* __restrict__ lnqw, const float* __restrict__ lnqb,
    const float* __restrict__ lnkw, const float* __restrict__ lnkb,
    unsigned short* __restrict__ Qbn, unsigned short* __restrict__ Kimg,
    unsigned short* __restrict__ Vimg)
{
  __shared__ __align__(16) unsigned short sh[36864];  // As 256x72 | Bs 256x72
  unsigned short* As = sh;
  unsigned short* Bs = sh + 256 * 72;

  const int tid = threadIdx.x;
  const int w   = tid >> 6;      // 0..7, rows w*32..+31
  const int l   = tid & 63;
  const int lm  = l & 31;
  const int lh  = l >> 5;
  const int z   = blockIdx.y;
  const int m0  = blockIdx.x * 256;
  const int bb  = m0 >> 12;      // batch (256 | 4096)

  const unsigned short* Bt = qkvT + (size_t)z * DEMB * DEMB;

  f32x16 o[8];
#pragma unroll
  for (int t = 0; t < 8; ++t)
#pragma unroll
    for (int r = 0; r < 16; ++r) o[t][r] = 0.f;

  const int fr = tid >> 4;          // 0..31, A rows fr+32i
  const int fc = (tid & 15) * 4;    // A col

  float4 arf[8];
  bf16x8 brb[4];

  // preload k0 = 0
#pragma unroll
  for (int i = 0; i < 8; ++i)
    arf[i] = *(const float4*)(x + (size_t)(m0 + fr + 32 * i) * DEMB + fc);
#pragma unroll
  for (int i = 0; i < 4; ++i) {
    const int c = tid + 512 * i;
    brb[i] = *(const bf16x8*)(Bt + (size_t)(c >> 3) * DEMB + (c & 7) * 8);
  }

  for (int k0 = 0; k0 < DEMB; k0 += 64) {
    __syncthreads();
#pragma unroll
    for (int i = 0; i < 8; ++i) {
      ushort4 u;
      u.x = f2bf(arf[i].x); u.y = f2bf(arf[i].y);
      u.z = f2bf(arf[i].z); u.w = f2bf(arf[i].w);
      *(ushort4*)&As[(fr + 32 * i) * 72 + fc] = u;
    }
#pragma unroll
    for (int i = 0; i < 4; ++i) {
      const int c = tid + 512 * i;
      *(bf16x8*)&Bs[(c >> 3) * 72 + (c & 7) * 8] = brb[i];
    }
    __syncthreads();

    if (k0 + 64 < DEMB) {
      const int kn = k0 + 64;
#pragma unroll
      for (int i = 0; i < 8; ++i)
        arf[i] = *(const float4*)(x + (size_t)(m0 + fr + 32 * i) * DEMB + kn + fc);
#pragma unroll
      for (int i = 0; i < 4; ++i) {
        const int c = tid + 512 * i;
        brb[i] = *(const bf16x8*)(Bt + (size_t)(c >> 3) * DEMB + kn + (c & 7) * 8);
      }
    }

#pragma unroll
    for (int ks = 0; ks < 4; ++ks) {
      bf16x8 a = *(const bf16x8*)&As[(w * 32 + lm) * 72 + ks * 16 + lh * 8];
#pragma unroll
      for (int t = 0; t < 8; ++t) {
        bf16x8 b = *(const bf16x8*)&Bs[(t * 32 + lm) * 72 + ks * 16 + lh * 8];
        o[t] = __builtin_amdgcn_mfma_f32_32x32x16_bf16(a, b, o[t], 0, 0, 0);
      }
    }
  }

  __syncthreads();   // all LDS frag reads done before epilogue reuse

  if (z < 2) {
    // ---- LayerNorm in-register, write Qbn (linear) or Kimg (tile image) ----
    const float* wp = z ? lnkw : lnqw;
    const float* bp = z ? lnkb : lnqb;
    float wc[8], bc[8];
#pragma unroll
    for (int t = 0; t < 8; ++t) { wc[t] = wp[t * 32 + lm]; bc[t] = bp[t * 32 + lm]; }
#pragma unroll
    for (int r = 0; r < 16; ++r) {
      float sv = 0.f, sq = 0.f;
#pragma unroll
      for (int t = 0; t < 8; ++t) { const float v = o[t][r]; sv += v; sq += v * v; }
#pragma unroll
      for (int d = 1; d < 32; d <<= 1) { sv += __shfl_xor(sv, d, 64); sq += __shfl_xor(sq, d, 64); }
      const float mean = sv * (1.f / DEMB);
      const float rs = rsqrtf(sq * (1.f / DEMB) - mean * mean + 1e-5f);
      const int token = m0 + w * 32 + (r & 3) + 8 * (r >> 2) + 4 * lh;
      if (z == 0) {
        unsigned short* dst = Qbn + (size_t)token * DEMB;
#pragma unroll
        for (int t = 0; t < 8; ++t)
          dst[t * 32 + lm] = f2bf((o[t][r] - mean) * rs * wc[t] + bc[t]);
      } else {
        const int t5 = token & 4095;
        unsigned short* dst =
            Kimg + (size_t)(bb * 128 + (t5 >> 5)) * KIMG_STRIDE + (t5 & 31) * 264;
#pragma unroll
        for (int t = 0; t < 8; ++t)
          dst[t * 32 + lm] = f2bf((o[t][r] - mean) * rs * wc[t] + bc[t]);
      }
    }
  } else {
    // ---- V: transpose via LDS (pitch 130 shorts = 65 dw, conflict-free) ----
#pragma unroll
    for (int h = 0; h < 2; ++h) {
      if (h) __syncthreads();
#pragma unroll
      for (int t2 = 0; t2 < 4; ++t2) {
        const int t = h * 4 + t2;
#pragma unroll
        for (int r = 0; r < 16; ++r) {
          const int row = w * 32 + (r & 3) + 8 * (r >> 2) + 4 * lh;
          sh[row * 130 + t2 * 32 + lm] = f2bf(o[t][r]);
        }
      }
      __syncthreads();
      const int d2 = tid & 127;          // local d within half
      const int tq = tid >> 7;           // 0..3, tokens tq*64..+63
      const int d  = h * 128 + d2;
#pragma unroll
      for (int j = 0; j < 16; ++j) {
        const int tok0 = tq * 64 + j * 4;
        ushort4 v;
        v.x = sh[(tok0 + 0) * 130 + d2];
        v.y = sh[(tok0 + 1) * 130 + d2];
        v.z = sh[(tok0 + 2) * 130 + d2];
        v.w = sh[(tok0 + 3) * 130 + d2];
        const int gtok = m0 + tok0;
        const int kt = (gtok & 4095) >> 5;
        *(ushort4*)(Vimg + (size_t)(bb * 128 + kt) * VIMG_STRIDE + d * 40 + (tok0 & 31)) = v;
      }
    }
  }
}

// ---------------------------------------------------------------------------
// bf16 MFMA GEMM, bf16 in / bf16 out, leaky-relu. C = act(A @ Bt^T).
// 128x128 tile, 4 waves, 2x2 MFMA subtiles/wave, pipelined K-loop.
// ---------------------------------------------------------------------------
__global__ __launch_bounds__(256, 3) void gemm_ffn_kernel(
    const unsigned short* __restrict__ A, const unsigned short* __restrict__ Bt,
    unsigned short* __restrict__ C, int M, int N, int K)
{
  __shared__ __align__(16) unsigned short As[128 * 72];
  __shared__ __align__(16) unsigned short Bs[128 * 72];

  const int tid = threadIdx.x;
  const int w   = tid >> 6;
  const int wm  = w >> 1, wn = w & 1;
  const int l   = tid & 63;
  const int lm  = l & 31;
  const int lh  = l >> 5;

  const int m0    = blockIdx.x * 128;
  const int nbase = blockIdx.y * 128;

  f32x16 acc00, acc01, acc10, acc11;
#pragma unroll
  for (int r = 0; r < 16; ++r) { acc00[r] = 0.f; acc01[r] = 0.f; acc10[r] = 0.f; acc11[r] = 0.f; }

  const int lr = tid >> 3;
  const int lc = (tid & 7) * 8;

  bf16x8 arb[4], brb[4];

#pragma unroll
  for (int i = 0; i < 4; ++i) {
    arb[i] = *(const bf16x8*)(A  + (size_t)(m0 + i * 32 + lr) * K + lc);
    brb[i] = *(const bf16x8*)(Bt + (size_t)(nbase + i * 32 + lr) * K + lc);
  }

  for (int k0 = 0; k0 < K; k0 += 64) {
    __syncthreads();
#pragma unroll
    for (int i = 0; i < 4; ++i) {
      *(bf16x8*)&As[(i * 32 + lr) * 72 + lc] = arb[i];
      *(bf16x8*)&Bs[(i * 32 + lr) * 72 + lc] = brb[i];
    }
    __syncthreads();

    if (k0 + 64 < K) {
      const int kn = k0 + 64;
#pragma unroll
      for (int i = 0; i < 4; ++i) {
        arb[i] = *(const bf16x8*)(A  + (size_t)(m0 + i * 32 + lr) * K + kn + lc);
        brb[i] = *(const bf16x8*)(Bt + (size_t)(nbase + i * 32 + lr) * K + kn + lc);
      }
    }

#pragma unroll
    for (int ks = 0; ks < 4; ++ks) {
      bf16x8 a0 = *(const bf16x8*)&As[(wm * 64 + lm)      * 72 + ks * 16 + lh * 8];
      bf16x8 a1 = *(const bf16x8*)&As[(wm * 64 + 32 + lm) * 72 + ks * 16 + lh * 8];
      bf16x8 b0 = *(const bf16x8*)&Bs[(wn * 64 + lm)      * 72 + ks * 16 + lh * 8];
      bf16x8 b1 = *(const bf16x8*)&Bs[(wn * 64 + 32 + lm) * 72 + ks * 16 + lh * 8];
      acc00 = __builtin_amdgcn_mfma_f32_32x32x16_bf16(a0, b0, acc00, 0, 0, 0);
      acc01 = __builtin_amdgcn_mfma_f32_32x32x16_bf16(a0, b1, acc01, 0, 0, 0);
      acc10 = __builtin_amdgcn_mfma_f32_32x32x16_bf16(a1, b0, acc10, 0, 0, 0);
      acc11 = __builtin_amdgcn_mfma_f32_32x32x16_bf16(a1, b1, acc11, 0, 0, 0);
    }
  }

  const f32x16* accs[4] = { &acc00, &acc01, &acc10, &acc11 };
#pragma unroll
  for (int am = 0; am < 2; ++am)
#pragma unroll
    for (int bn = 0; bn < 2; ++bn) {
      const f32x16& a = *accs[am * 2 + bn];
#pragma unroll
      for (int r = 0; r < 16; ++r) {
        const int m = m0 + wm * 64 + am * 32 + (r & 3) + 8 * (r >> 2) + 4 * lh;
        const int n = nbase + wn * 64 + bn * 32 + lm;
        float v = a[r];
        v = v > 0.f ? v : 0.2f * v;
        C[(size_t)m * N + n] = f2bf(v);
      }
    }
}

// Out = 0.7f * (Xin + LN(Y)), Y bf16; aliasing Out==Xin safe.
__global__ __launch_bounds__(256) void ln_res_bf16_kernel(
    const unsigned short* __restrict__ Y, const float* __restrict__ Xin,
    const float* __restrict__ w, const float* __restrict__ b,
    float* __restrict__ Out)
{
  const int lane = threadIdx.x & 63;
  const size_t row = (size_t)blockIdx.x * 4 + (threadIdx.x >> 6);
  ushort4 u = *(const ushort4*)&Y[row * DEMB + lane * 4];
  float y0 = bf2f(u.x), y1 = bf2f(u.y), y2 = bf2f(u.z), y3 = bf2f(u.w);
  float s  = y0 + y1 + y2 + y3;
  float sq = y0 * y0 + y1 * y1 + y2 * y2 + y3 * y3;
#pragma unroll
  for (int o = 32; o > 0; o >>= 1) { s += __shfl_down(s, o); sq += __shfl_down(sq, o); }
  s = __shfl(s, 0); sq = __shfl(sq, 0);
  const float m  = s * (1.f / DEMB);
  const float rs = rsqrtf(sq * (1.f / DEMB) - m * m + 1e-5f);
  const float4 wv = *(const float4*)&w[lane * 4];
  const float4 bv = *(const float4*)&b[lane * 4];
  const float4 xi = *(const float4*)&Xin[row * DEMB + lane * 4];
  float4 o;
  o.x = 0.7f * (xi.x + (y0 - m) * rs * wv.x + bv.x);
  o.y = 0.7f * (xi.y + (y1 - m) * rs * wv.y + bv.y);
  o.z = 0.7f * (xi.z + (y2 - m) * rs * wv.z + bv.z);
  o.w = 0.7f * (xi.w + (y3 - m) * rs * wv.w + bv.w);
  *(float4*)&Out[row * DEMB + lane * 4] = o;
}

// ---------------------------------------------------------------------------
// Split-K MFMA flash attention (v4, best measured): QK(j) 1:1-interleaved
// with PV(j-1) so the 16-deep QK dep chain is spaced by independent PV MFMAs.
// SM(j) post-barrier, overlapping the other resident block's MFMA window.
// One barrier/tile; K dbuf + V dbuf; LDS 75776 B -> 2 blocks/CU (the two
// decorrelated barrier groups per CU are the key: one block's SM/barrier
// bubble is filled by the other's MFMA window).
// ---------------------------------------------------------------------------
__global__ __launch_bounds__(256, 2) void attn_split_kernel(
    const unsigned short* __restrict__ Qb, const unsigned short* __restrict__ Kimg,
    const unsigned short* __restrict__ Vimg, unsigned short* __restrict__ Opart,
    float* __restrict__ lpart)
{
  __shared__ __align__(16) unsigned short Ks[2][KIMG_STRIDE];   // 34816 B
  __shared__ __align__(16) unsigned short Vs[2][VIMG_STRIDE];   // 40960 B

  const int tid = threadIdx.x;
  const int w   = tid >> 6;          // 0..3
  const int l   = tid & 63;
  const int lm  = l & 31;
  const int lh  = l >> 5;

  const int lin = blockIdx.x;        // 0..511
  const int xcd = lin & 7;
  const int idx = lin >> 3;          // 0..63
  const int b     = xcd >> 1;
  const int split = (xcd & 1) * 2 + (idx & 1);
  const int q0    = (idx >> 1) * 128;

  const unsigned short* Qbase  = Qb + (size_t)b * TSEQ * DEMB;
  const unsigned short* Ktiles = Kimg + (size_t)(b * 128 + split * 32) * KIMG_STRIDE;
  const unsigned short* Vtiles = Vimg + (size_t)(b * 128 + split * 32) * VIMG_STRIDE;

  // Q fragments (B-operand of swapped QK): lane holds q-row lm of this wave
  bf16x8 qf[16];
  {
    const unsigned short* qrow = Qbase + (size_t)(q0 + w * 32 + lm) * DEMB + lh * 8;
#pragma unroll
    for (int ks = 0; ks < 16; ++ks) qf[ks] = *(const bf16x8*)(qrow + ks * 16);
  }

  f32x16 o[8];
#pragma unroll
  for (int t = 0; t < 8; ++t)
#pragma unroll
    for (int r = 0; r < 16; ++r) o[t][r] = 0.f;
  float psum = 0.f;

  bf16x8 pva, pvb;   // P(j) fragments, produced by SM(j), consumed by PV(j)

  auto DMAK = [&](int t, int buf) {
    const unsigned short* kp = Ktiles + (size_t)t * KIMG_STRIDE;
#pragma unroll
    for (int i = 0; i < 5; ++i) {
      const int c = w + 4 * i;
      if (c < 17) async16(&Ks[buf][c * 512], kp + c * 512 + l * 8);
    }
  };
  auto DMAV = [&](int t, int buf) {
    const unsigned short* vp = Vtiles + (size_t)t * VIMG_STRIDE;
#pragma unroll
    for (int i = 0; i < 5; ++i) {
      const int c = w + 4 * i;                 // 0..19, all used
      async16(&Vs[buf][c * 512], vp + c * 512 + l * 8);
    }
  };
  auto QK = [&](int buf) {
    f32x16 s;
#pragma unroll
    for (int r = 0; r < 16; ++r) s[r] = 0.f;
    const unsigned short* Kp = &Ks[buf][0];
#pragma unroll
    for (int ks = 0; ks < 16; ++ks) {
      bf16x8 kf = *(const bf16x8*)&Kp[lm * 264 + ks * 16 + lh * 8];
      s = __builtin_amdgcn_mfma_f32_32x32x16_bf16(kf, qf[ks], s, 0, 0, 0);
    }
    return s;
  };
  auto PV = [&](int buf) {
    const unsigned short* Vp = &Vs[buf][0];
#pragma unroll
    for (int t = 0; t < 8; ++t) {
      bf16x8 vf0 = *(const bf16x8*)&Vp[(t * 32 + lm) * 40 + lh * 8];
      o[t] = __builtin_amdgcn_mfma_f32_32x32x16_bf16(pva, vf0, o[t], 0, 0, 0);
      bf16x8 vf1 = *(const bf16x8*)&Vp[(t * 32 + lm) * 40 + 16 + lh * 8];
      o[t] = __builtin_amdgcn_mfma_f32_32x32x16_bf16(pvb, vf1, o[t], 0, 0, 0);
    }
  };
  auto SM = [&](const f32x16& s) {
    // s[r] = score(q=lm, tok=(r&3)+8*(r>>2)+4*lh); fixed-offset softmax.
    float e[16];
#pragma unroll
    for (int i = 0; i < 16; ++i)
      e[i] = exp2f(s[i] * 0.09016844335f - 11.541560327f);
    const float t0 = (e[0] + e[1]) + (e[2] + e[3]);
    const float t1 = (e[4] + e[5]) + (e[6] + e[7]);
    const float t2 = (e[8] + e[9]) + (e[10] + e[11]);
    const float t3 = (e[12] + e[13]) + (e[14] + e[15]);
    psum += (t0 + t1) + (t2 + t3);
    unsigned pk[8];
#pragma unroll
    for (int i = 0; i < 8; ++i)
      asm("v_cvt_pk_bf16_f32 %0, %1, %2" : "=v"(pk[i]) : "v"(e[2 * i]), "v"(e[2 * i + 1]));
    plswap(pk[0], pk[2]);   // -> dwords 0,2 of pva (tokens 0..15)
    plswap(pk[1], pk[3]);   // -> dwords 1,3 of pva
    plswap(pk[4], pk[6]);   // -> dwords 0,2 of pvb (tokens 16..31)
    plswap(pk[5], pk[7]);   // -> dwords 1,3 of pvb
    union U8 { unsigned u[4]; bf16x8 v; } A, B;
    A.u[0] = pk[0]; A.u[1] = pk[1]; A.u[2] = pk[2]; A.u[3] = pk[3];
    B.u[0] = pk[4]; B.u[1] = pk[5]; B.u[2] = pk[6]; B.u[3] = pk[7];
    pva = A.v; pvb = B.v;
  };

  // ---- prologue ----
  DMAK(0, 0); DMAV(0, 0);
  __syncthreads();                    // K0,V0 landed (vmcnt0 drain)
  DMAK(1, 1);
  f32x16 s = QK(0);
  __syncthreads();                    // all waves done reading Ks[0]; K1 landed
  DMAV(1, 1);
  SM(s);                              // -> pva/pvb = P(0)

  // ---- steady state: seg j = QK(j) 1:1-interleaved with PV(j-1), then
  //      sync, DMA-V(j+1), SM(j). Alternation keeps the s-chain's dependent
  //      MFMAs 2 issue-slots apart (o[t] chains fill the latency). ----
  for (int j = 1; j < NT; ++j) {
    const int kc = j & 1, kn = kc ^ 1;
    if (j + 1 < NT) DMAK(j + 1, kn);  // WAR ok: QK(j-1) read Ks[kn] pre-sync(j-1)
    const unsigned short* Kp = &Ks[kc][0];
    const unsigned short* Vp = &Vs[kn][0];
    f32x16 sn;
#pragma unroll
    for (int r = 0; r < 16; ++r) sn[r] = 0.f;
    __builtin_amdgcn_s_setprio(1);
#pragma unroll
    for (int i = 0; i < 16; ++i) {
      bf16x8 kf = *(const bf16x8*)&Kp[lm * 264 + i * 16 + lh * 8];
      sn = __builtin_amdgcn_mfma_f32_32x32x16_bf16(kf, qf[i], sn, 0, 0, 0);
      if (i < 8) {
        bf16x8 vf = *(const bf16x8*)&Vp[(i * 32 + lm) * 40 + lh * 8];
        o[i] = __builtin_amdgcn_mfma_f32_32x32x16_bf16(pva, vf, o[i], 0, 0, 0);
      } else {
        bf16x8 vf = *(const bf16x8*)&Vp[((i - 8) * 32 + lm) * 40 + 16 + lh * 8];
        o[i - 8] = __builtin_amdgcn_mfma_f32_32x32x16_bf16(pvb, vf, o[i - 8], 0, 0, 0);
      }
    }
    __builtin_amdgcn_s_setprio(0);
    s = sn;
    __syncthreads();                  // cross-wave fence + vmcnt0 (drains K(j+1), V(j))
    if (j + 1 < NT) DMAV(j + 1, kn);  // buffer just released by PV(j-1)
    SM(s);                            // -> P(j); overlaps other block's MFMA window
  }

  // ---- epilogue: last PV ----
  PV((NT - 1) & 1);

  // denominator for q-row lm: this lane's tokens + partner half (lh^1)
  const float tot = psum + __shfl_xor(psum, 32, 64);

  unsigned short* Ob =
      Opart + ((size_t)split * NTOK + (size_t)b * TSEQ + q0 + w * 32) * DEMB;
  float* lb = lpart + (size_t)split * NTOK + (size_t)b * TSEQ + q0 + w * 32;
#pragma unroll
  for (int r = 0; r < 16; ++r) {
    const int row = (r & 3) + ((r >> 2) << 3) + (lh << 2);
#pragma unroll
    for (int t = 0; t < 8; ++t)
      Ob[(size_t)row * DEMB + t * 32 + lm] = f2bf(o[t][r]);
  }
  if (lh == 0) lb[lm] = tot;
}

// ---------------------------------------------------------------------------
// Combine partials + attn LayerNorm + residual; emits fp32 x1 and bf16 copy.
// ---------------------------------------------------------------------------
__global__ __launch_bounds__(256) void combine_lnres_kernel(
    const unsigned short* __restrict__ Opart, const float* __restrict__ lpart,
    const float* __restrict__ Xin, const float* __restrict__ w,
    const float* __restrict__ b, float* __restrict__ Out,
    unsigned short* __restrict__ Outb)
{
  const int lane = threadIdx.x & 63;
  const size_t row = (size_t)blockIdx.x * 4 + (threadIdx.x >> 6);
  float4 acc = make_float4(0.f, 0.f, 0.f, 0.f);
  float lt = 0.f;
#pragma unroll
  for (int p = 0; p < SPLITS; ++p) {
    const ushort4 u = *(const ushort4*)&Opart[((size_t)p * NTOK + row) * DEMB + lane * 4];
    acc.x += bf2f(u.x); acc.y += bf2f(u.y);
    acc.z += bf2f(u.z); acc.w += bf2f(u.w);
    lt += lpart[(size_t)p * NTOK + row];
  }
  const float inv = 1.f / lt;
  const float y0 = acc.x * inv, y1 = acc.y * inv, y2 = acc.z * inv, y3 = acc.w * inv;
  float s  = y0 + y1 + y2 + y3;
  float sq = y0 * y0 + y1 * y1 + y2 * y2 + y3 * y3;
#pragma unroll
  for (int o = 32; o > 0; o >>= 1) { s += __shfl_down(s, o); sq += __shfl_down(sq, o); }
  s = __shfl(s, 0); sq = __shfl(sq, 0);
  const float m  = s * (1.f / DEMB);
  const float rs = rsqrtf(sq * (1.f / DEMB) - m * m + 1e-5f);
  const float4 wv = *(const float4*)&w[lane * 4];
  const float4 bv = *(const float4*)&b[lane * 4];
  const float4 xi = *(const float4*)&Xin[row * DEMB + lane * 4];
  float4 o;
  o.x = 0.7f * (xi.x + (y0 - m) * rs * wv.x + bv.x);
  o.y = 0.7f * (xi.y + (y1 - m) * rs * wv.y + bv.y);
  o.z = 0.7f * (xi.z + (y2 - m) * rs * wv.z + bv.z);
  o.w = 0.7f * (xi.w + (y3 - m) * rs * wv.w + bv.w);
  *(float4*)&Out[row * DEMB + lane * 4] = o;
  ushort4 ob;
  ob.x = f2bf(o.x); ob.y = f2bf(o.y); ob.z = f2bf(o.z); ob.w = f2bf(o.w);
  *(ushort4*)&Outb[row * DEMB + lane * 4] = ob;
}

// ---------------------------------------------------------------------------
extern "C" void kernel_launch(void* const* d_in, const int* in_sizes, int n_in,
                              void* d_out, int out_size, void* d_ws, size_t ws_size,
                              hipStream_t stream)
{
  (void)in_sizes; (void)n_in; (void)out_size; (void)ws_size;
  const float* x    = (const float*)d_in[0];
  const float* qkv  = (const float*)d_in[1];
  const float* lnqw = (const float*)d_in[2];
  const float* lnqb = (const float*)d_in[3];
  const float* lnkw = (const float*)d_in[4];
  const float* lnkb = (const float*)d_in[5];
  const float* lnaw = (const float*)d_in[6];
  const float* lnab = (const float*)d_in[7];
  const float* w1   = (const float*)d_in[8];
  const float* w2   = (const float*)d_in[9];
  const float* lnfw = (const float*)d_in[10];
  const float* lnfb = (const float*)d_in[11];
  float* out = (float*)d_out;

  // byte-offset workspace (lifetimes disjoint):
  //   Qbn[0,8) Kimg[8,17) Vimg[17,28) Opart[28,60) lpart@60
  //   x1b[0,8) (Qbn dead after attn)  H[8,24) (Kimg/Vimg dead)
  //   Y2b[28,36) (Opart dead after combine)  qkvT@60.5 w1b@61 w2b@61.25
  char* W = (char*)d_ws;
  const size_t MB = 1 << 20;
  unsigned short* Qbn   = (unsigned short*)(W + 0);
  unsigned short* Kimg  = (unsigned short*)(W + 8 * MB);    // 8.9 MB
  unsigned short* Vimg  = (unsigned short*)(W + 17 * MB);   // 10.5 MB
  unsigned short* Opart = (unsigned short*)(W + 28 * MB);   // 32 MB
  float*          lpart = (float*)(W + 60 * MB);            // 256 KB
  unsigned short* x1b   = (unsigned short*)(W + 0);
  unsigned short* H     = (unsigned short*)(W + 8 * MB);
  unsigned short* Y2b   = (unsigned short*)(W + 28 * MB);
  unsigned short* qkvT  = (unsigned short*)(W + 60 * MB + 512 * 1024);  // 384 KB
  unsigned short* w1b   = (unsigned short*)(W + 61 * MB);               // 256 KB
  unsigned short* w2b   = (unsigned short*)(W + 61 * MB + 256 * 1024);  // 256 KB

  const dim3 blk(256);

  // weight prep: qkv transpose+cast + w1/w2 cast
  prep_kernel<<<dim3(128, 5), blk, 0, stream>>>(qkv, w1, w2, qkvT, w1b, w2b);

  // fused QKV projection + LN(Q/K) + V-transpose (192 blocks, all resident)
  qkvln_kernel<<<dim3(NTOK / 256, 3), dim3(512), 0, stream>>>(
      x, qkvT, lnqw, lnqb, lnkw, lnkb, Qbn, Kimg, Vimg);

  // attention (split-K, interleaved QK/PV pipeline) + combine/LN/residual
  attn_split_kernel<<<dim3(512), dim3(256), 0, stream>>>(Qbn, Kimg, Vimg, Opart, lpart);
  combine_lnres_kernel<<<NTOK / 4, blk, 0, stream>>>(Opart, lpart, x, lnaw, lnab, out, x1b);

  // FFN (bf16 weights, bf16 out)
  gemm_ffn_kernel<<<dim3(NTOK / 128, HID / 128), blk, 0, stream>>>(
      x1b, w1b, H, NTOK, HID, DEMB);
  gemm_ffn_kernel<<<dim3(NTOK / 128, DEMB / 128), blk, 0, stream>>>(
      H, w2b, Y2b, NTOK, DEMB, HID);

  // out = 0.7*(x1 + LN(y2))
  ln_res_bf16_kernel<<<NTOK / 4, blk, 0, stream>>>(Y2b, out, lnfw, lnfb, out);
}